// Round 7
// baseline (398.743 us; speedup 1.0000x reference)
//
#include <hip/hip_runtime.h>
#include <stdint.h>

#define NUM_ENTRIES 1000000
#define NUM_HINTS   32768
#define MAX_SUBSET  512
#define CHUNKS      5
#define ROW_BYTES   20
#define SLICES      8
#define SLICE_BYTES (NUM_ENTRIES / SLICES * ROW_BYTES)   // 2,500,000 B = 2.5 MB, fits 4 MB XCD L2
#define HPW         4                                    // hints per wave

typedef unsigned u32x4a4 __attribute__((ext_vector_type(4), aligned(4)));
typedef unsigned u32x2a4 __attribute__((ext_vector_type(2), aligned(4)));

// Phase-sliced gather: all co-resident waves sweep table slices 0..7 in
// lockstep-ish order; during pass p only slice p (2.5 MB) is gathered -> it
// stays L2-resident on every XCD. Indices live in registers (pre-scaled to
// byte offsets), so streams are read exactly once. 4 hints/wave, grid = 2048
// blocks = 8 blocks/CU -> whole grid is one co-resident cohort (needs <=64
// VGPR, forced via launch_bounds).
__global__ __launch_bounds__(256, 8) void hint_xor_kernel(
    const void* __restrict__ entries_v,
    const void* __restrict__ indices_v,
    const void* __restrict__ mask_v,
    int* __restrict__ out)
{
    const int wave  = threadIdx.x >> 6;
    const int lane  = threadIdx.x & 63;
    const int gw    = blockIdx.x * 4 + wave;
    const int hint0 = gw * HPW;

    // ---- layout detection (wave-uniform votes, FP <= 2^-64; guards against
    // harness dtype surprises, costs ~nothing) ----
    const unsigned* ew = (const unsigned*)entries_v;
    const unsigned* iw = (const unsigned*)indices_v;
    const unsigned* mw = (const unsigned*)mask_v;
    const unsigned es = ew[lane];
    const unsigned is = iw[lane];
    const unsigned ms = mw[lane];
    const bool odd = (lane & 1) != 0;
    const bool ent32   = __any(odd && (es & 0xC0000000u));
    const bool idx32   = __any(odd && (is != 0u));
    const bool m_bytes = __any((ms != 0u) && (ms != 1u) && (ms != 0x3f800000u));
    const bool m_odd_nz = __any(odd && (ms != 0u));
    const int  mstep = m_odd_nz ? 1 : 2;

    unsigned acc[HPW][CHUNKS];
    #pragma unroll
    for (int j = 0; j < HPW; ++j)
        #pragma unroll
        for (int c = 0; c < CHUNKS; ++c) acc[j][c] = 0u;

    if (ent32 && idx32 && m_bytes) {
        // ================= fast path (confirmed layouts) =================
        const int*           idxp  = (const int*)indices_v;
        const unsigned char* mp    = (const unsigned char*)mask_v;
        const char*          ebase = (const char*)entries_v;

        // prologue: lane owns slots [8*lane, 8*lane+8) of each of its 4 hints
        unsigned off[HPW][8];   // idx*20 byte offsets (<2^25, fits u32)
        unsigned mbits = 0;     // bit j*8+k = mask of hint j slot 8*lane+k
        #pragma unroll
        for (int j = 0; j < HPW; ++j) {
            const size_t base = (size_t)(hint0 + j) * MAX_SUBSET + 8u * lane;
            const u32x4a4 i0 = __builtin_nontemporal_load((const u32x4a4*)(idxp + base));
            const u32x4a4 i1 = __builtin_nontemporal_load((const u32x4a4*)(idxp + base + 4));
            off[j][0] = i0.x * 20u; off[j][1] = i0.y * 20u;
            off[j][2] = i0.z * 20u; off[j][3] = i0.w * 20u;
            off[j][4] = i1.x * 20u; off[j][5] = i1.y * 20u;
            off[j][6] = i1.z * 20u; off[j][7] = i1.w * 20u;
            const u32x2a4 mv = __builtin_nontemporal_load((const u32x2a4*)(mp + base));
            #pragma unroll
            for (int k = 0; k < 4; ++k) {
                if ((mv.x >> (8 * k)) & 0xFFu) mbits |= 1u << (j * 8 + k);
                if ((mv.y >> (8 * k)) & 0xFFu) mbits |= 1u << (j * 8 + 4 + k);
            }
        }

        // slice sweep: pass p gathers only from slice p (keeps p L2-resident
        // chip-wide). Runtime loop (not unrolled) to keep i-cache small and
        // phases crisp.
        #pragma unroll 1
        for (int p = 0; p < SLICES; ++p) {
            const unsigned lo = (unsigned)p * (unsigned)SLICE_BYTES;
            #pragma unroll
            for (int j = 0; j < HPW; ++j) {
                #pragma unroll
                for (int k = 0; k < 8; ++k) {
                    const unsigned o = off[j][k];
                    // in-slice test doubles as bounds guard (unsigned wrap)
                    const bool hit = ((mbits >> (j * 8 + k)) & 1u) &&
                                     (o - lo < (unsigned)SLICE_BYTES);
                    if (hit) {
                        const u32x4a4 q = *(const u32x4a4*)(ebase + o);
                        const unsigned t = *(const unsigned*)(ebase + o + 16);
                        acc[j][0] ^= q.x; acc[j][1] ^= q.y; acc[j][2] ^= q.z;
                        acc[j][3] ^= q.w; acc[j][4] ^= t;
                    }
                }
            }
        }
    } else {
        // ================= generic fallback (any layout) =================
        const int*           idx32p = (const int*)indices_v;
        const long long*     idx64p = (const long long*)indices_v;
        const unsigned char* m8p    = (const unsigned char*)mask_v;
        const unsigned*      m32p   = (const unsigned*)mask_v;

        #pragma unroll 1
        for (int j = 0; j < HPW; ++j) {
            const size_t rowoff = (size_t)(hint0 + j) * MAX_SUBSET;
            #pragma unroll 1
            for (int k = 0; k < 8; ++k) {
                const size_t s = rowoff + (size_t)(k * 64 + lane);
                long long idx = idx32 ? (long long)idx32p[s] : idx64p[s];
                unsigned mv = m_bytes ? (unsigned)m8p[s] : m32p[s * (size_t)mstep];
                const bool v = (mv != 0u) &&
                               ((unsigned long long)idx < (unsigned long long)NUM_ENTRIES);
                if (v) {
                    if (ent32) {
                        const unsigned* e = (const unsigned*)entries_v + (size_t)idx * 5u;
                        acc[j][0] ^= e[0]; acc[j][1] ^= e[1]; acc[j][2] ^= e[2];
                        acc[j][3] ^= e[3]; acc[j][4] ^= e[4];
                    } else {
                        const unsigned* e = (const unsigned*)entries_v + (size_t)idx * 10u;
                        acc[j][0] ^= e[0]; acc[j][1] ^= e[2]; acc[j][2] ^= e[4];
                        acc[j][3] ^= e[6]; acc[j][4] ^= e[8];
                    }
                }
            }
        }
    }

    // 64-lane XOR butterfly over all 20 accumulators
    #pragma unroll
    for (int o = 32; o >= 1; o >>= 1) {
        #pragma unroll
        for (int j = 0; j < HPW; ++j)
            #pragma unroll
            for (int c = 0; c < CHUNKS; ++c)
                acc[j][c] ^= (unsigned)__shfl_xor((int)acc[j][c], o, 64);
    }

    // coalesced epilogue: out[hint0*5 + lane] for lane < 20
    // (lane = j*5+c -> value acc[j][c], selected via compile-time chain)
    if (lane < HPW * CHUNKS) {
        unsigned v = 0;
        #pragma unroll
        for (int j = 0; j < HPW; ++j)
            #pragma unroll
            for (int c = 0; c < CHUNKS; ++c)
                v = (lane == j * CHUNKS + c) ? acc[j][c] : v;
        out[(size_t)hint0 * CHUNKS + lane] = (int)v;
    }
}

extern "C" void kernel_launch(void* const* d_in, const int* in_sizes, int n_in,
                              void* d_out, int out_size, void* d_ws, size_t ws_size,
                              hipStream_t stream) {
    const void* entries = d_in[0];
    const void* indices = d_in[1];
    const void* mask    = d_in[2];
    int*        out     = (int*)d_out;

    // 4 waves/block x 4 hints/wave = 16 hints/block -> 2048 blocks
    // (= 8 blocks/CU: whole grid co-resident, one phase cohort)
    hint_xor_kernel<<<NUM_HINTS / (4 * HPW), 256, 0, stream>>>(entries, indices, mask, out);
}